// Round 1
// baseline (430.099 us; speedup 1.0000x reference)
//
#include <hip/hip_runtime.h>

#define NT 32
#define EPSF 1e-8f

// ---------------- Gram kernel ----------------
// G = vecs @ vecs^T, vecs is (32, D) fp32 row-major.
// Per wave: lanes form (cj in 0..3) x (pi in 0..3) x (pk in 0..3); lane owns an
// 8x8 patch of the 32x32 output, cj parallelizes columns. 64-column tiles are
// staged col-major in LDS (pitch 36 -> 16B-aligned b128 reads, 2-way bank alias
// only). Register prefetch pipelines global loads behind compute; no block-wide
// barrier in the K-loop (per-wave private tiles, lgkm fences for LDS ordering).
#define TILE_COLS 64
#define COL_PITCH 36
#define GR_THREADS 256
#define WAVES_PB 4
#define TILES_PW 16   // cols/wave = 1024, cols/block = 4096

__global__ __launch_bounds__(GR_THREADS, 2)
void gram_kernel(const float* __restrict__ vecs, double* __restrict__ Gd, int D)
{
    __shared__ float tile[WAVES_PB][TILE_COLS * COL_PITCH];
    __shared__ float Gpart[NT * NT];

    const int tid  = threadIdx.x;
    const int wave = tid >> 6;
    const int lane = tid & 63;

    for (int e = tid; e < NT * NT; e += GR_THREADS) Gpart[e] = 0.0f;
    __syncthreads();

    const int cj = lane >> 4;          // column subgroup 0..3
    const int p  = lane & 15;
    const int pi = p >> 2;             // patch rows 8*pi..8*pi+7
    const int pk = p & 3;              // patch cols 8*pk..8*pk+7

    const int lrow = lane >> 4;        // staging: 4 rows per load instr
    const int lcol = (lane & 15) << 2; // staging col offset 0..60

    float acc[8][8];
#pragma unroll
    for (int r = 0; r < 8; r++)
#pragma unroll
        for (int c = 0; c < 8; c++) acc[r][c] = 0.0f;

    float* my = tile[wave];
    const long colbase0 = (long)blockIdx.x * (WAVES_PB * TILES_PW * TILE_COLS)
                        + (long)wave * (TILES_PW * TILE_COLS);

    // prefetch tile 0 into registers
    float4 pre[8];
#pragma unroll
    for (int rr = 0; rr < 8; rr++) {
        const int row = (rr << 2) + lrow;
        pre[rr] = *(const float4*)(vecs + (long)row * D + colbase0 + lcol);
    }

    for (int t = 0; t < TILES_PW; t++) {
        __threadfence_block();  // prior tile's ds_reads done before overwrite
        // transpose-store prefetched tile: col-major LDS
#pragma unroll
        for (int rr = 0; rr < 8; rr++) {
            const int row = (rr << 2) + lrow;
            my[(lcol + 0) * COL_PITCH + row] = pre[rr].x;
            my[(lcol + 1) * COL_PITCH + row] = pre[rr].y;
            my[(lcol + 2) * COL_PITCH + row] = pre[rr].z;
            my[(lcol + 3) * COL_PITCH + row] = pre[rr].w;
        }
        __threadfence_block();  // ds_writes visible before ds_reads
        // issue next tile's global loads; they fly during compute below
        if (t + 1 < TILES_PW) {
            const long cb = colbase0 + (long)(t + 1) * TILE_COLS;
#pragma unroll
            for (int rr = 0; rr < 8; rr++) {
                const int row = (rr << 2) + lrow;
                pre[rr] = *(const float4*)(vecs + (long)row * D + cb + lcol);
            }
        }
#pragma unroll
        for (int jt = 0; jt < 16; jt++) {
            const int j = (jt << 2) + cj;
            const float* col = my + j * COL_PITCH;
            const float4 a0 = *(const float4*)(col + 8 * pi);
            const float4 a1 = *(const float4*)(col + 8 * pi + 4);
            const float4 b0 = *(const float4*)(col + 8 * pk);
            const float4 b1 = *(const float4*)(col + 8 * pk + 4);
            const float a[8] = {a0.x, a0.y, a0.z, a0.w, a1.x, a1.y, a1.z, a1.w};
            const float b[8] = {b0.x, b0.y, b0.z, b0.w, b1.x, b1.y, b1.z, b1.w};
#pragma unroll
            for (int r = 0; r < 8; r++)
#pragma unroll
                for (int c = 0; c < 8; c++)
                    acc[r][c] = fmaf(a[r], b[c], acc[r][c]);
        }
    }

    // fold the cj column-split (lanes l, l+16, l+32, l+48 share a patch)
#pragma unroll
    for (int r = 0; r < 8; r++)
#pragma unroll
        for (int c = 0; c < 8; c++) {
            float v = acc[r][c];
            v += __shfl_xor(v, 16);
            v += __shfl_xor(v, 32);
            if (lane < 16)
                atomicAdd(&Gpart[(8 * pi + r) * NT + (8 * pk + c)], v);
        }
    __syncthreads();
    for (int e = tid; e < NT * NT; e += GR_THREADS)
        atomicAdd(&Gd[e], (double)Gpart[e]);
}

// ---------------- Solver kernel ----------------
__device__ __forceinline__ float bsum32(float v) {
#pragma unroll
    for (int m = 1; m < 32; m <<= 1) v += __shfl_xor(v, m);
    return v;
}
__device__ __forceinline__ float bmin32(float v) {
#pragma unroll
    for (int m = 1; m < 32; m <<= 1) v = fminf(v, __shfl_xor(v, m));
    return v;
}

__global__ __launch_bounds__(64)
void solver_kernel(const double* __restrict__ Gd, float* __restrict__ out)
{
    __shared__ float Gsh[NT * 33];
    const int lane = threadIdx.x;  // one wave

    for (int t2 = 0; t2 < 16; t2++) {
        int e = t2 * 64 + lane;
        Gsh[(e >> 5) * 33 + (e & 31)] = (float)Gd[e];
    }
    __syncthreads();

    float Grow[NT];
#pragma unroll
    for (int k = 0; k < NT; k++)
        Grow[k] = (lane < NT) ? Gsh[lane * 33 + k] : 0.0f;

    // ---- planar init: argmin over all 496 (a<b) pairs ----
    float bestCost = INFINITY, bestGamma = 0.0f;
    int bestEnc = 0x7FFFFFFF;
    for (int a = 0; a < NT - 1; a++) {
        int b = a + 1 + lane;
        if (b < NT) {
            float v11 = Gsh[a * 33 + a];
            float v12 = Gsh[a * 33 + b];
            float v22 = Gsh[b * 33 + b];
            float g = (v22 - v12) / (v11 + v22 - 2.0f * v12 + EPSF);
            float c = v22 + g * (v12 - v22);
            float gamma = (v12 >= v22) ? 0.0f : g;
            float cost  = (v12 >= v22) ? v22 : c;
            if (v12 >= v11) { gamma = 1.0f; cost = v11; }
            int enc = a * NT + b;   // preserves triu linear order for tie-break
            if (cost < bestCost) { bestCost = cost; bestEnc = enc; bestGamma = gamma; }
        }
    }
#pragma unroll
    for (int m = 1; m < 64; m <<= 1) {
        float oc = __shfl_xor(bestCost, m);
        int   oe = __shfl_xor(bestEnc, m);
        float og = __shfl_xor(bestGamma, m);
        if (oc < bestCost || (oc == bestCost && oe < bestEnc)) {
            bestCost = oc; bestEnc = oe; bestGamma = og;
        }
    }
    const int bi = bestEnc >> 5, bj = bestEnc & 31;

    float sol = 0.0f;
    if (lane == bi) sol = bestGamma;
    if (lane == bj) sol = 1.0f - bestGamma;

    for (int it = 0; it < 250; it++) {
        // Gsol[i] = sum_k G[i][k] * sol[k]
        float s0 = 0, s1 = 0, s2 = 0, s3 = 0;
#pragma unroll
        for (int k = 0; k < NT; k += 4) {
            s0 = fmaf(Grow[k + 0], __shfl(sol, k + 0), s0);
            s1 = fmaf(Grow[k + 1], __shfl(sol, k + 1), s1);
            s2 = fmaf(Grow[k + 2], __shfl(sol, k + 2), s2);
            s3 = fmaf(Grow[k + 3], __shfl(sol, k + 3), s3);
        }
        float Gsol = (s0 + s1) + (s2 + s3);

        // ---- next_point ----
        float grad = -Gsol;
        float proj = grad - bsum32(grad) * 0.03125f;  // /32 exact

        float tm1 = (proj < 0.0f) ? (-sol / proj) : INFINITY;
        float tm2 = (proj > 0.0f) ? ((1.0f - sol) / proj) : INFINITY;
        float m1 = bmin32((tm1 > 1e-7f) ? tm1 : INFINITY);
        float m2 = bmin32((tm2 > 1e-7f) ? tm2 : INFINITY);
        float t = __builtin_isinf(m1) ? 1.0f : m1;
        t = fminf(t, m2);
        float nxt = fmaf(proj, t, sol);

        // ---- simplex projection: bitonic sort desc over lanes 0..31 ----
        float s = nxt;
#pragma unroll
        for (int k = 2; k <= 32; k <<= 1)
#pragma unroll
            for (int j = k >> 1; j >= 1; j >>= 1) {
                float pp = __shfl_xor(s, j);
                bool descSeg = (lane & k) == 0;  // inverted net => descending
                bool lower = (lane & j) == 0;
                float mn = fminf(s, pp), mx = fmaxf(s, pp);
                s = (descSeg == lower) ? mx : mn;
            }
        // inclusive prefix sum over 32
        float cs = s;
#pragma unroll
        for (int d = 1; d < 32; d <<= 1) {
            float pp = __shfl_up(cs, d, 32);
            if ((lane & 31) >= d) cs += pp;
        }
        float tmpm = (cs - 1.0f) / (float)((lane & 31) + 1);
        float snext = __shfl_down(s, 1, 32);
        bool cond = ((lane & 31) < 31) && (tmpm > snext);
        unsigned long long bal = __ballot(cond ? 1 : 0) & 0x7FFFFFFFull;
        float tmax;
        if (bal != 0ULL) {
            int first = __builtin_ctzll(bal);
            tmax = __shfl(tmpm, first);
        } else {
            tmax = __shfl(tmpm, 31);
        }
        float newp = fmaxf(nxt - tmax, 0.0f);
        if (lane >= NT) newp = 0.0f;

        // Gn[i] = sum_k G[i][k] * newp[k]
        float n0 = 0, n1 = 0, n2 = 0, n3 = 0;
#pragma unroll
        for (int k = 0; k < NT; k += 4) {
            n0 = fmaf(Grow[k + 0], __shfl(newp, k + 0), n0);
            n1 = fmaf(Grow[k + 1], __shfl(newp, k + 1), n1);
            n2 = fmaf(Grow[k + 2], __shfl(newp, k + 2), n2);
            n3 = fmaf(Grow[k + 3], __shfl(newp, k + 3), n3);
        }
        float Gn = (n0 + n1) + (n2 + n3);

        float v11 = bsum32(sol * Gsol);
        float v12 = bsum32(sol * Gn);
        float v22 = bsum32(newp * Gn);

        float g = (v22 - v12) / (v11 + v22 - 2.0f * v12 + EPSF);
        float gamma = (v12 >= v22) ? 0.0f : g;
        gamma = (v12 >= v11) ? 1.0f : gamma;

        float new_sol = gamma * sol + (1.0f - gamma) * newp;
        float diff = bsum32(fabsf(new_sol - sol));
        diff = __shfl(diff, 0);
        if (diff < 1e-6f) break;   // freeze: output the OLD sol (ref semantics)
        sol = new_sol;
    }
    if (lane < NT) out[lane] = sol;
}

extern "C" void kernel_launch(void* const* d_in, const int* in_sizes, int n_in,
                              void* d_out, int out_size, void* d_ws, size_t ws_size,
                              hipStream_t stream) {
    const float* vecs = (const float*)d_in[0];
    float* out = (float*)d_out;
    double* Gd = (double*)d_ws;          // 1024 doubles = 8 KB
    const int D = in_sizes[0] / NT;      // 2097152

    hipMemsetAsync(Gd, 0, NT * NT * sizeof(double), stream);

    const int cols_per_block = WAVES_PB * TILES_PW * TILE_COLS;  // 4096
    const int grid = D / cols_per_block;                          // 512
    gram_kernel<<<grid, GR_THREADS, 0, stream>>>(vecs, Gd, D);
    solver_kernel<<<1, 64, 0, stream>>>(Gd, out);
}